// Round 9
// baseline (460.894 us; speedup 1.0000x reference)
//
#include <hip/hip_runtime.h>

#define N_NODES 50000
#define N_EDGES 800000
#define N_GRAPHS 256
#define F 100  // hidden dim

#define SCAN_B 512
#define SCAN_NB 98          // 98*512 = 50176 >= 50001
#define SCAN_PAD (SCAN_NB * SCAN_B)

#define PART_SZ 6250        // 8 dst partitions * 6250 = 50000
#define FILL_CHUNK 2048

#define SROW 72             // LDS row stride in shorts
#define NB 112              // feature half-tile (224-row padded weights, 2 halves)

typedef __attribute__((ext_vector_type(8))) short bf16x8;
typedef __attribute__((ext_vector_type(4))) float f32x4;
typedef unsigned short ushort_t;
typedef unsigned int uint_t;

__device__ inline ushort_t f2bf(float f) {  // RNE float->bf16
  uint_t u = __float_as_uint(f);
  uint_t r = (u + 0x7fffu + ((u >> 16) & 1u)) >> 16;
  return (ushort_t)r;
}

// ---------------- CSR build (counting sort by dst, rebuilt every call) ----------------
// hist/fill dst-range partitioned by blockIdx&7 (XCD round-robin heuristic) so csr/cursor
// atomics+scatters for a dst range stay in one XCD's L2 (R4->R6: fill 55 -> ~20 us).

__global__ __launch_bounds__(256) void hist_kernel(const int* __restrict__ dst,
                                                   int* __restrict__ cnt, int E) {
  int part = blockIdx.x & 7;
  int lo = part * PART_SZ, hi = lo + PART_SZ;
  int base = (blockIdx.x >> 3) * FILL_CHUNK;
  int end = base + FILL_CHUNK; if (end > E) end = E;
  for (int i = base + threadIdx.x; i < end; i += 256) {
    int d = dst[i];
    if (d >= lo && d < hi) atomicAdd(&cnt[d], 1);
  }
}

__global__ __launch_bounds__(SCAN_B) void scan1_kernel(const int* __restrict__ cnt,
                                                       int* __restrict__ excl,
                                                       int* __restrict__ bsum) {
  __shared__ int sh[SCAN_B];
  int t = threadIdx.x;
  int i = blockIdx.x * SCAN_B + t;
  int v = cnt[i];
  sh[t] = v;
  __syncthreads();
  for (int off = 1; off < SCAN_B; off <<= 1) {
    int u = (t >= off) ? sh[t - off] : 0;
    __syncthreads();
    sh[t] += u;
    __syncthreads();
  }
  excl[i] = sh[t] - v;
  if (t == SCAN_B - 1) bsum[blockIdx.x] = sh[t];
}

__global__ __launch_bounds__(128) void scan2_kernel(int* __restrict__ bsum) {
  __shared__ int sh[128];
  int t = threadIdx.x;
  int v = (t < SCAN_NB) ? bsum[t] : 0;
  sh[t] = v;
  __syncthreads();
  for (int off = 1; off < 128; off <<= 1) {
    int u = (t >= off) ? sh[t - off] : 0;
    __syncthreads();
    sh[t] += u;
    __syncthreads();
  }
  if (t < SCAN_NB) bsum[t] = sh[t] - v;
}

__global__ __launch_bounds__(SCAN_B) void scan3_kernel(const int* __restrict__ excl,
                                                       const int* __restrict__ bsum,
                                                       int* __restrict__ offs,
                                                       int* __restrict__ cursor) {
  int i = blockIdx.x * SCAN_B + threadIdx.x;
  int v = excl[i] + bsum[blockIdx.x];
  if (i <= N_NODES) { offs[i] = v; cursor[i] = v; }
}

__global__ __launch_bounds__(256) void fill_kernel(const int* __restrict__ src,
                                                   const int* __restrict__ dst,
                                                   int* __restrict__ cursor,
                                                   int* __restrict__ csr_src, int E) {
  int part = blockIdx.x & 7;
  int lo = part * PART_SZ, hi = lo + PART_SZ;
  int base = (blockIdx.x >> 3) * FILL_CHUNK;
  int end = base + FILL_CHUNK; if (end > E) end = E;
  for (int i = base + threadIdx.x; i < end; i += 256) {
    int d = dst[i];
    if (d >= lo && d < hi) {
      int p = atomicAdd(&cursor[d], 1);
      csr_src[p] = src[i];
    }
  }
}

// ---------------- weight packing: [224][Kp] bf16, zero-padded (rows 200..223 zero) -------------

__global__ void pack_w1_kernel(const float* __restrict__ w1_rel, const float* __restrict__ w1_root,
                               ushort_t* __restrict__ Wp1) {
  int row = blockIdx.x;  // 224
  for (int k = threadIdx.x; k < 384; k += 128) {
    float v = 0.f;
    if (k < 336) {
      if (row < 100) v = w1_rel[row * 336 + k];
      else if (row < 200) v = w1_root[(row - 100) * 336 + k];
    }
    Wp1[(size_t)row * 384 + k] = f2bf(v);
  }
}

__global__ void pack_w_kernel(const float* __restrict__ w_rel, const float* __restrict__ w_root,
                              ushort_t* __restrict__ Wp) {
  int row = blockIdx.x;  // 224
  int l = blockIdx.y;    // 4
  int k = threadIdx.x;   // 128
  float v = 0.f;
  if (k < 100) {
    if (row < 100) v = w_rel[((size_t)l * 100 + row) * 100 + k];
    else if (row < 200) v = w_root[((size_t)l * 100 + row - 100) * 100 + k];
  }
  Wp[((size_t)l * 224 + row) * 128 + k] = f2bf(v);
}

// ---------------- MFMA conv: Zrel = A@Wrel.T (bf16), Zroot = A@Wroot.T + b ----------------
// R9: feature-split tile 64 nodes x 112 feats (grid.y = 2 halves of the 224-row padded
// weights). R8 PMC showed conv at 1.24 TB/s = outstanding-loads x latency bound
// (Little's law at ~12 waves/CU); splitting halves LDS (40->25 KB) and acc VGPRs,
// doubling resident blocks/CU (3->6) and in-flight bytes. K-order per output unchanged.
// BK=64 register-prefetch double buffer kept from R7.

template <bool AF32>
__global__ __launch_bounds__(256) void conv_mfma(
    const void* __restrict__ Aptr, const ushort_t* __restrict__ Wp,
    const float* __restrict__ bias,
    ushort_t* __restrict__ Zrel, ushort_t* __restrict__ Zroot, int Kp) {
  __shared__ short alds[64 * SROW];    //  9.2 KB
  __shared__ short blds[NB * SROW];    // 16.1 KB
  __shared__ float bias_s[104];

  int tid = threadIdx.x;
  int n0 = blockIdx.x * 64;
  int h = blockIdx.y;                  // feature half: rows [h*NB, h*NB+NB) of Wp
  if (tid < 100) bias_s[tid] = bias[tid];

  f32x4 acc[7];
#pragma unroll
  for (int b = 0; b < 7; ++b) acc[b] = (f32x4)0.f;

  int w = tid >> 6, lane = tid & 63, q = lane >> 4, m16 = lane & 15;

  // staging: A = 512 16B-chunks (2/thread), B = NB*8 = 896 chunks (<=4/thread)
  int ar[2], aq[2];
#pragma unroll
  for (int u = 0; u < 2; ++u) { int c = tid + u * 256; ar[u] = c >> 3; aq[u] = c & 7; }

  bf16x8 areg[2], breg[4];

  auto load_chunk = [&](int k0) {
#pragma unroll
    for (int u = 0; u < 2; ++u) {
      int node = n0 + ar[u];
      int k = k0 + aq[u] * 8;
      bf16x8 val = (bf16x8)0;
      if (AF32) {
        if (node < N_NODES && k < 336) {
          const float* p = (const float*)Aptr + (size_t)node * 336 + k;
          float4 f0 = *(const float4*)p;
          float4 f1 = *(const float4*)(p + 4);
          val[0] = (short)f2bf(f0.x); val[1] = (short)f2bf(f0.y);
          val[2] = (short)f2bf(f0.z); val[3] = (short)f2bf(f0.w);
          val[4] = (short)f2bf(f1.x); val[5] = (short)f2bf(f1.y);
          val[6] = (short)f2bf(f1.z); val[7] = (short)f2bf(f1.w);
        }
      } else {
        if (node < N_NODES)
          val = *(const bf16x8*)((const short*)Aptr + (size_t)node * 128 + k);
      }
      areg[u] = val;
    }
#pragma unroll
    for (int u = 0; u < 4; ++u) {
      int c = tid + u * 256;
      if (c < NB * 8) {
        int r = c >> 3, qq = c & 7;
        breg[u] = *(const bf16x8*)((const short*)Wp + (size_t)(h * NB + r) * Kp + k0 + qq * 8);
      }
    }
  };

  load_chunk(0);

  for (int k0 = 0; k0 < Kp; k0 += 64) {
#pragma unroll
    for (int u = 0; u < 2; ++u)
      *(bf16x8*)&alds[ar[u] * SROW + aq[u] * 8] = areg[u];
#pragma unroll
    for (int u = 0; u < 4; ++u) {
      int c = tid + u * 256;
      if (c < NB * 8) {
        int r = c >> 3, qq = c & 7;
        *(bf16x8*)&blds[r * SROW + qq * 8] = breg[u];
      }
    }
    __syncthreads();
    if (k0 + 64 < Kp) load_chunk(k0 + 64);
#pragma unroll
    for (int s = 0; s < 2; ++s) {
      bf16x8 a = *(const bf16x8*)&alds[(w * 16 + m16) * SROW + s * 32 + q * 8];
#pragma unroll
      for (int b = 0; b < 7; ++b) {
        bf16x8 bf = *(const bf16x8*)&blds[(b * 16 + m16) * SROW + s * 32 + q * 8];
        acc[b] = __builtin_amdgcn_mfma_f32_16x16x32_bf16(a, bf, acc[b], 0, 0, 0);
      }
    }
    __syncthreads();
  }

  // epilogue: node = n0 + w*16 + q*4 + r ; feat n = h*NB + b*16 + m16
  int node_base = n0 + w * 16 + q * 4;
#pragma unroll
  for (int b = 0; b < 7; ++b) {
    int n = h * NB + b * 16 + m16;
#pragma unroll
    for (int r = 0; r < 4; ++r) {
      int node = node_base + r;
      if (node >= N_NODES) continue;
      float v = acc[b][r];
      if (n < 100) {
        Zrel[(size_t)node * 100 + n] = f2bf(v);
      } else if (n < 200) {
        Zroot[(size_t)node * 100 + (n - 100)] = f2bf(v + bias_s[n - 100]);
      }
    }
  }
}

// ---------------- gather: H[i] = relu(Zroot[i] + sum Zrel[src]) in bf16, padded to 128 ----------
// R8 form: one coalesced vector load of up to 64 csr indices, v_readlane broadcast,
// independent row loads in groups of 8. Near the L3 random-line throughput roofline.

__global__ __launch_bounds__(256) void gather_bf16(
    const ushort_t* __restrict__ Zrel, const ushort_t* __restrict__ Zroot,
    const int* __restrict__ offs, const int* __restrict__ csr,
    ushort_t* __restrict__ H) {
  int node = blockIdx.x * 4 + (threadIdx.x >> 6);
  node = __builtin_amdgcn_readfirstlane(node);  // wave-uniform -> scalar offs loads
  int lane = threadIdx.x & 63;
  int off = (lane < 50 ? lane : 49) * 2;  // ushort offset within 100-col row

  uint_t z = *(const uint_t*)(Zroot + (size_t)node * 100 + off);
  float p0[8], p1[8];
#pragma unroll
  for (int u = 0; u < 8; ++u) { p0[u] = 0.f; p1[u] = 0.f; }
  p0[0] = __uint_as_float(z << 16);
  p1[0] = __uint_as_float(z & 0xffff0000u);

  int s = offs[node], e = offs[node + 1];
  for (int j = s; j < e; j += 64) {
    int take = e - j; if (take > 64) take = 64;
    int vidx = (lane < take) ? csr[j + lane] : 0;  // one coalesced 256B vector load
    int u = 0;
    for (; u + 8 <= take; u += 8) {
      uint_t zz[8];
#pragma unroll
      for (int t = 0; t < 8; ++t) {
        int idx = __builtin_amdgcn_readlane(vidx, u + t);
        zz[t] = *(const uint_t*)(Zrel + (size_t)idx * 100 + off);
      }
#pragma unroll
      for (int t = 0; t < 8; ++t) {
        p0[t] += __uint_as_float(zz[t] << 16);
        p1[t] += __uint_as_float(zz[t] & 0xffff0000u);
      }
    }
    int cnt = take - u;  // 0..7, wave-uniform
    if (cnt > 0) {
      uint_t zz[7];
#pragma unroll
      for (int t = 0; t < 7; ++t) {
        if (t < cnt) {
          int idx = __builtin_amdgcn_readlane(vidx, u + t);
          zz[t] = *(const uint_t*)(Zrel + (size_t)idx * 100 + off);
        }
      }
#pragma unroll
      for (int t = 0; t < 7; ++t) {
        if (t < cnt) {
          p0[t] += __uint_as_float(zz[t] << 16);
          p1[t] += __uint_as_float(zz[t] & 0xffff0000u);
        }
      }
    }
  }
  float a0 = ((p0[0] + p0[1]) + (p0[2] + p0[3])) + ((p0[4] + p0[5]) + (p0[6] + p0[7]));
  float a1 = ((p1[0] + p1[1]) + (p1[2] + p1[3])) + ((p1[4] + p1[5]) + (p1[6] + p1[7]));
  a0 = fmaxf(a0, 0.f);
  a1 = fmaxf(a1, 0.f);
  uint_t outp = (uint_t)f2bf(a0) | ((uint_t)f2bf(a1) << 16);
  if (lane >= 50) outp = 0u;  // pad cols 100..127 = 0
  *(uint_t*)(H + (size_t)node * 128 + lane * 2) = outp;
}

// ---------------- global mean pool: 1 block/graph, 16 node-rows x 64 lanes ----------------

__global__ __launch_bounds__(1024) void pool_kernel(const ushort_t* __restrict__ H,
                                                    const int* __restrict__ batch,
                                                    float* __restrict__ pooled) {
  int g = blockIdx.x;
  int t = threadIdx.x;
  int lo = 0, hi = N_NODES;
  while (lo < hi) { int mid = (lo + hi) >> 1; if (batch[mid] < g) lo = mid + 1; else hi = mid; }
  int s = lo;
  hi = N_NODES;
  while (lo < hi) { int mid = (lo + hi) >> 1; if (batch[mid] <= g) lo = mid + 1; else hi = mid; }
  int e = lo;

  int row = t >> 6;      // 16 node-rows
  int lane = t & 63;
  int off = (lane < 50 ? lane : 49) * 2;
  float a0 = 0.f, a1 = 0.f;
  for (int n = s + row; n < e; n += 16) {
    uint_t z = *(const uint_t*)(H + (size_t)n * 128 + off);
    a0 += __uint_as_float(z << 16);
    a1 += __uint_as_float(z & 0xffff0000u);
  }
  __shared__ float sh[16][104];
  if (lane < 50) { sh[row][lane * 2] = a0; sh[row][lane * 2 + 1] = a1; }
  __syncthreads();
  if (t < 100) {
    float acc = 0.f;
#pragma unroll
    for (int r = 0; r < 16; ++r) acc += sh[r][t];
    int cnt = e - s;
    float d = (cnt > 0) ? (float)cnt : 1.f;
    pooled[(size_t)g * F + t] = acc / d;
  }
}

// ---------------- fused 3-layer MLP head (fp32) ----------------

__global__ void mlp_kernel(const float* __restrict__ pooled,
                           const float* __restrict__ lw1, const float* __restrict__ lb1,
                           const float* __restrict__ lw2, const float* __restrict__ lb2,
                           const float* __restrict__ lw3, const float* __restrict__ lb3,
                           float* __restrict__ out) {
  int g = blockIdx.x;
  int t = threadIdx.x;
  __shared__ float r0[F], r1[F], r2[F];
  if (t < F) r0[t] = pooled[(size_t)g * F + t];
  __syncthreads();
  if (t < F) {
    float s = lb1[t];
    for (int k = 0; k < F; ++k) s += r0[k] * lw1[t * F + k];
    r1[t] = fmaxf(s, 0.f);
  }
  __syncthreads();
  if (t < F) {
    float s = lb2[t];
    for (int k = 0; k < F; ++k) s += r1[k] * lw2[t * F + k];
    r2[t] = fmaxf(s, 0.f);
  }
  __syncthreads();
  if (t < 29) {
    float s = lb3[t];
    for (int k = 0; k < F; ++k) s += r2[k] * lw3[t * F + k];
    out[g * 29 + t] = s;
  }
}

// ---------------- launch ------------------------------------------------------------------------

extern "C" void kernel_launch(void* const* d_in, const int* in_sizes, int n_in,
                              void* d_out, int out_size, void* d_ws, size_t ws_size,
                              hipStream_t stream) {
  const float* x       = (const float*)d_in[0];
  const int*   ei      = (const int*)d_in[1];
  const int*   batch   = (const int*)d_in[2];
  const float* w1_rel  = (const float*)d_in[3];
  const float* w1_root = (const float*)d_in[4];
  const float* b1      = (const float*)d_in[5];
  const float* w_rel   = (const float*)d_in[6];
  const float* w_root  = (const float*)d_in[7];
  const float* bvec    = (const float*)d_in[8];
  const float* lw1     = (const float*)d_in[9];
  const float* lb1     = (const float*)d_in[10];
  const float* lw2     = (const float*)d_in[11];
  const float* lb2     = (const float*)d_in[12];
  const float* lw3     = (const float*)d_in[13];
  const float* lb3     = (const float*)d_in[14];
  float* out = (float*)d_out;

  // workspace layout
  char* ws = (char*)d_ws;
  size_t o = 0;
  auto alloc = [&](size_t bytes) { void* p = ws + o; o = (o + bytes + 511) & ~(size_t)511; return p; };
  ushort_t* H    = (ushort_t*)alloc((size_t)N_NODES * 128 * 2);   // 12.8 MB
  ushort_t* Zrel = (ushort_t*)alloc((size_t)N_NODES * 100 * 2);   // 10 MB
  ushort_t* Zroot= (ushort_t*)alloc((size_t)N_NODES * 100 * 2);   // 10 MB
  ushort_t* Wp1  = (ushort_t*)alloc((size_t)224 * 384 * 2);
  ushort_t* Wp   = (ushort_t*)alloc((size_t)4 * 224 * 128 * 2);
  float*    pooled = (float*)alloc((size_t)N_GRAPHS * F * 4);
  int* cnt    = (int*)alloc((size_t)SCAN_PAD * 4);
  int* excl   = (int*)alloc((size_t)SCAN_PAD * 4);
  int* bsum   = (int*)alloc((size_t)128 * 4);
  int* offs   = (int*)alloc((size_t)(N_NODES + 1) * 4);
  int* cursor = (int*)alloc((size_t)(N_NODES + 1) * 4);
  int* csr    = (int*)alloc((size_t)N_EDGES * 4);

  const int E = N_EDGES;
  const int* srcv = ei;
  const int* dstv = ei + E;

  int nchunk = (E + FILL_CHUNK - 1) / FILL_CHUNK;  // 391
  // CSR build (parallel 3-phase scan; hist/fill dst-partitioned 8-way)
  hipMemsetAsync(cnt, 0, (size_t)SCAN_PAD * sizeof(int), stream);
  hist_kernel<<<nchunk * 8, 256, 0, stream>>>(dstv, cnt, E);
  scan1_kernel<<<SCAN_NB, SCAN_B, 0, stream>>>(cnt, excl, bsum);
  scan2_kernel<<<1, 128, 0, stream>>>(bsum);
  scan3_kernel<<<SCAN_NB, SCAN_B, 0, stream>>>(excl, bsum, offs, cursor);
  fill_kernel<<<nchunk * 8, 256, 0, stream>>>(srcv, dstv, cursor, csr, E);

  // weight packing (224 rows, padded)
  pack_w1_kernel<<<224, 128, 0, stream>>>(w1_rel, w1_root, Wp1);
  pack_w_kernel<<<dim3(224, 4), 128, 0, stream>>>(w_rel, w_root, Wp);

  dim3 mmgrid((N_NODES + 63) / 64, 2);  // 782 x 2 feature-halves
  // layer 1: A = x fp32 [50000][336], Kp=384 (padded)
  conv_mfma<true><<<mmgrid, 256, 0, stream>>>(x, Wp1, b1, Zrel, Zroot, 384);
  gather_bf16<<<N_NODES / 4, 256, 0, stream>>>(Zrel, Zroot, offs, csr, H);
  // layers 2..5: A = H bf16 [50000][128], Kp=128
  for (int l = 0; l < 4; ++l) {
    conv_mfma<false><<<mmgrid, 256, 0, stream>>>(H, Wp + (size_t)l * 224 * 128,
                                                 bvec + (size_t)l * F, Zrel, Zroot, 128);
    gather_bf16<<<N_NODES / 4, 256, 0, stream>>>(Zrel, Zroot, offs, csr, H);
  }
  pool_kernel<<<N_GRAPHS, 1024, 0, stream>>>(H, batch, pooled);
  mlp_kernel<<<N_GRAPHS, 128, 0, stream>>>(pooled, lw1, lb1, lw2, lb2, lw3, lb3, out);
}